// Round 20
// baseline (241.368 us; speedup 1.0000x reference)
//
#include <hip/hip_runtime.h>
#include <hip/hip_bf16.h>

#define T_TOK 8192
#define DDIM 1024
#define HDIM 1024
#define NEXP 8
#define KTOP 2
#define NROWS (T_TOK * KTOP)

typedef __attribute__((ext_vector_type(8))) short bf16x8;
typedef __attribute__((ext_vector_type(8))) unsigned short u16x8;
typedef __attribute__((ext_vector_type(4))) float f32x4;

__device__ __forceinline__ unsigned short f2bf(float f) {
    unsigned u = __builtin_bit_cast(unsigned, f);
    u += 0x7fffu + ((u >> 16) & 1u);   // RNE
    return (unsigned short)(u >> 16);
}
__device__ __forceinline__ float bf2f(unsigned short h) {
    return __builtin_bit_cast(float, (unsigned)h << 16);
}

// async global->LDS, 16B per lane; LDS dest wave-uniform base + lane*16.
__device__ __forceinline__ void gll16(const unsigned short* g, const unsigned short* l) {
    __builtin_amdgcn_global_load_lds(
        (const __attribute__((address_space(1))) unsigned int*)g,
        (__attribute__((address_space(3))) unsigned int*)l, 16, 0, 0);
}

// ---------------- prep kernels ----------------

__global__ __launch_bounds__(256) void cvt_bf16_k(const float* __restrict__ in,
                                                  unsigned short* __restrict__ out, int n4) {
    int i = blockIdx.x * 256 + threadIdx.x;
    if (i >= n4) return;
    float4 v = ((const float4*)in)[i];
    ushort4 o;
    o.x = f2bf(v.x); o.y = f2bf(v.y); o.z = f2bf(v.z); o.w = f2bf(v.w);
    ((ushort4*)out)[i] = o;
}

// merged transpose+cast, 64x64 tiles, 16B/lane coalesced writes (r15, verified).
__global__ __launch_bounds__(256) void transpose_cast3_k(
    const float* __restrict__ w1, const float* __restrict__ w2,
    const float* __restrict__ w3, unsigned short* __restrict__ o1,
    unsigned short* __restrict__ o2, unsigned short* __restrict__ o3) {
    __shared__ float tile[64][65];
    int z = blockIdx.z;
    int which = z >> 3, m = z & 7;
    const float* src = (which == 0 ? w1 : which == 1 ? w2 : w3) + (size_t)m * DDIM * HDIM;
    unsigned short* dst = (which == 0 ? o1 : which == 1 ? o2 : o3) + (size_t)m * DDIM * HDIM;
    int c0 = blockIdx.x * 64, r0 = blockIdx.y * 64;
    int t = threadIdx.x;
    int rr = t >> 4;
    int cc = (t & 15) * 4;
#pragma unroll
    for (int p = 0; p < 4; ++p) {
        float4 v = *(const float4*)&src[(size_t)(r0 + rr + p * 16) * HDIM + c0 + cc];
        tile[rr + p * 16][cc]     = v.x;
        tile[rr + p * 16][cc + 1] = v.y;
        tile[rr + p * 16][cc + 2] = v.z;
        tile[rr + p * 16][cc + 3] = v.w;
    }
    __syncthreads();
    int rb = (t & 7) * 8;
    int oc = t >> 3;
#pragma unroll
    for (int q = 0; q < 2; ++q) {
        int c = oc + q * 32;
        u16x8 o;
#pragma unroll
        for (int j = 0; j < 8; ++j)
            o[j] = f2bf(tile[rb + j][c]);
        *(u16x8*)&dst[(size_t)(c0 + c) * DDIM + r0 + rb] = o;
    }
}

// ---- FUSED gate+up: 128x128, A LDS-staged, B DIRECT-TO-REG (r20) --------------
// h = silu(gather(x)@W1+b1) * (gather(x)@W2+b2).
// r19 model: kernel jointly LDS-pipe(3050cyc) / MFMA(2480cyc) bound per
// iter-pair; register wall (236 regs) pins 2 waves/SIMD. Fix: B-fragments map
// to CONTIGUOUS 16B in the B^T layout -> load straight to VGPRs from L2
// (B panels XCD/L2-resident; Common-mistake #7: don't stage what caches).
// Replaces ds_read_b128 with global 16B loads at the SAME program points ->
// identical register liveness (~108 VGPR); LDS traffic 144KB -> 48KB per
// block-iter. A keeps gll16 + swizzle (gather; 2x intra-block reuse).
// Swizzle pair (A only) verified r5-r19. XCD-chunked grid.

constexpr int BMk = 128, BNk = 128, BKk = 64;

__global__ __launch_bounds__(256, 2) void gemm128_fused_k(
    const unsigned short* __restrict__ A, const int* __restrict__ rowidx,
    const unsigned short* __restrict__ B1t, const unsigned short* __restrict__ B2t,
    const float* __restrict__ b1E, const float* __restrict__ b2E,
    unsigned short* __restrict__ Out, const int* __restrict__ offsets) {
    const int N = HDIM, K = DDIM, lda = DDIM;
    __shared__ __attribute__((aligned(16))) unsigned short lds[8192];  // 16 KiB (A only)

    const int nbn = N / BNk;                          // 8
    int l = (blockIdx.x & 7) * 128 + (blockIdx.x >> 3);
    int brow = l / nbn, bcol = l % nbn;
    int row0 = brow * BMk, col0 = bcol * BNk;
    int e = 0;
    while (offsets[e + 1] <= row0) ++e;

    const unsigned short* B1e = B1t + (size_t)e * N * K;
    const unsigned short* B2e = B2t + (size_t)e * N * K;
    const float* b1 = b1E + (size_t)e * N;
    const float* b2 = b2E + (size_t)e * N;

    int tid = threadIdx.x;
    int lane = tid & 63, wid = tid >> 6;
    int wr = wid >> 1, wc = wid & 1;                  // 2x2 wave grid
    int l15 = lane & 15, l4 = lane >> 4;

    // A staging (gll16, inverse-swizzled source)
    int srow = lane >> 3;
    int c8 = ((lane & 7) ^ srow) * 8;
    const unsigned short* aS[4];
#pragma unroll
    for (int q = 0; q < 4; ++q) {
        int gr = row0 + (wid * 4 + q) * 8 + srow;
        aS[q] = A + (size_t)rowidx[gr] * lda + c8;
    }

    // B direct-to-reg pointers: fragment (col, k-chunk) is contiguous 16B in B^T
    const unsigned short* b1P[4];
    const unsigned short* b2P[4];
#pragma unroll
    for (int ni = 0; ni < 4; ++ni) {
        int c = col0 + wc * 64 + ni * 16 + l15;
        b1P[ni] = B1e + (size_t)c * K + l4 * 8;
        b2P[ni] = B2e + (size_t)c * K + l4 * 8;
    }

    const char* LB = (const char*)lds;
    int arow = (wr * 64 + l15) * 128;
    int cx = l15 & 7;
    int ch0 = (l4 ^ cx) * 16;
    int ch1 = ((4 + l4) ^ cx) * 16;

    f32x4 acc1[4][4] = {};
    f32x4 acc2[4][4] = {};

#pragma unroll 1
    for (int t = 0; t < K / BKk; ++t) {
        int k0 = t * BKk;
#pragma unroll
        for (int q = 0; q < 4; ++q)
            gll16(aS[q] + k0, lds + (wid * 4 + q) * 512);
        __syncthreads();   // A landed; co-resident block hides the drain
#pragma unroll
        for (int s = 0; s < 2; ++s) {
            int ch = s ? ch1 : ch0;
            int kk = k0 + s * 32;
            bf16x8 fa[4], fb1[4], fb2[4];
#pragma unroll
            for (int mi = 0; mi < 4; ++mi)
                fa[mi] = *(const bf16x8*)(LB + arow + mi * 2048 + ch);
#pragma unroll
            for (int ni = 0; ni < 4; ++ni) {
                fb1[ni] = *(const bf16x8*)(b1P[ni] + kk);
                fb2[ni] = *(const bf16x8*)(b2P[ni] + kk);
            }
#pragma unroll
            for (int mi = 0; mi < 4; ++mi)
#pragma unroll
                for (int ni = 0; ni < 4; ++ni) {
                    acc1[mi][ni] = __builtin_amdgcn_mfma_f32_16x16x32_bf16(
                        fa[mi], fb1[ni], acc1[mi][ni], 0, 0, 0);
                    acc2[mi][ni] = __builtin_amdgcn_mfma_f32_16x16x32_bf16(
                        fa[mi], fb2[ni], acc2[mi][ni], 0, 0, 0);
                }
        }
        __syncthreads();   // A reads done before next stage overwrites
    }

    float bv1[4], bv2[4];
#pragma unroll
    for (int ni = 0; ni < 4; ++ni) {
        int c = col0 + wc * 64 + ni * 16 + l15;
        bv1[ni] = b1[c];
        bv2[ni] = b2[c];
    }

#pragma unroll
    for (int mi = 0; mi < 4; ++mi) {
        int orow_b = row0 + wr * 64 + mi * 16 + l4 * 4;
#pragma unroll
        for (int ni = 0; ni < 4; ++ni) {
            int ocol = col0 + wc * 64 + ni * 16 + l15;
#pragma unroll
            for (int q = 0; q < 4; ++q) {
                float g = acc1[mi][ni][q] + bv1[ni];
                float u = acc2[mi][ni][q] + bv2[ni];
                float s = g / (1.0f + __expf(-g));
                Out[(size_t)(orow_b + q) * N + ocol] = f2bf(s * u);
            }
        }
    }
}

// ---- DUAL-ROW y-GEMM: 256x128, A1/A2 LDS-staged, B DIRECT-TO-REG --------------
// y = h @ Wout^T + bout. Two 128-row tiles share one B-tile (r19, 42us);
// B now loaded straight to VGPRs (same rationale as fused). LDS = 32KB (A1+A2).

__global__ __launch_bounds__(256, 2) void gemm128_dualrow_k(
    const unsigned short* __restrict__ A, int lda,
    const unsigned short* __restrict__ Bt, const float* __restrict__ biasE,
    unsigned short* __restrict__ Out, const int* __restrict__ offsets,
    int N, int K) {
    __shared__ __attribute__((aligned(16))) unsigned short lds[16384];  // 32 KiB

    const int nbn = N / BNk;                          // 8
    int l = (blockIdx.x & 7) * 64 + (blockIdx.x >> 3);
    int brow = l / nbn, bcol = l % nbn;               // brow: 0..63 (256-row units)
    int row0 = brow * 256, col0 = bcol * BNk;
    int e = 0;
    while (offsets[e + 1] <= row0) ++e;

    const unsigned short* Bte = Bt + (size_t)e * N * K;
    const float* bias = biasE + (size_t)e * N;

    int tid = threadIdx.x;
    int lane = tid & 63, wid = tid >> 6;
    int wr = wid >> 1, wc = wid & 1;                  // 2x2 wave grid
    int l15 = lane & 15, l4 = lane >> 4;

    int srow = lane >> 3;
    int c8 = ((lane & 7) ^ srow) * 8;
    const unsigned short* a1S[4];
    const unsigned short* a2S[4];
#pragma unroll
    for (int q = 0; q < 4; ++q) {
        int g = wid * 4 + q;
        a1S[q] = A + (size_t)(row0 + g * 8 + srow) * lda + c8;
        a2S[q] = A + (size_t)(row0 + 128 + g * 8 + srow) * lda + c8;
    }

    const unsigned short* bP[4];
#pragma unroll
    for (int ni = 0; ni < 4; ++ni) {
        int c = col0 + wc * 64 + ni * 16 + l15;
        bP[ni] = Bte + (size_t)c * K + l4 * 8;
    }

    const char* LB = (const char*)lds;
    int arow = (wr * 64 + l15) * 128;                 // byte, within each A tile
    int cx = l15 & 7;
    int ch0 = (l4 ^ cx) * 16;
    int ch1 = ((4 + l4) ^ cx) * 16;

    f32x4 acc1[4][4] = {};
    f32x4 acc2[4][4] = {};

#pragma unroll 1
    for (int t = 0; t < K / BKk; ++t) {
        int k0 = t * BKk;
#pragma unroll
        for (int q = 0; q < 4; ++q) {
            gll16(a1S[q] + k0, lds + (wid * 4 + q) * 512);
            gll16(a2S[q] + k0, lds + 8192 + (wid * 4 + q) * 512);
        }
        __syncthreads();   // A landed; co-resident block hides the drain
#pragma unroll
        for (int s = 0; s < 2; ++s) {
            int ch = s ? ch1 : ch0;
            int kk = k0 + s * 32;
            bf16x8 fa1[4], fa2[4], fb[4];
#pragma unroll
            for (int mi = 0; mi < 4; ++mi) {
                fa1[mi] = *(const bf16x8*)(LB + arow + mi * 2048 + ch);
                fa2[mi] = *(const bf16x8*)(LB + 16384 + arow + mi * 2048 + ch);
            }
#pragma unroll
            for (int ni = 0; ni < 4; ++ni)
                fb[ni] = *(const bf16x8*)(bP[ni] + kk);
#pragma unroll
            for (int mi = 0; mi < 4; ++mi)
#pragma unroll
                for (int ni = 0; ni < 4; ++ni) {
                    acc1[mi][ni] = __builtin_amdgcn_mfma_f32_16x16x32_bf16(
                        fa1[mi], fb[ni], acc1[mi][ni], 0, 0, 0);
                    acc2[mi][ni] = __builtin_amdgcn_mfma_f32_16x16x32_bf16(
                        fa2[mi], fb[ni], acc2[mi][ni], 0, 0, 0);
                }
        }
        __syncthreads();   // A reads done before next stage overwrites
    }

    float bv[4];
#pragma unroll
    for (int ni = 0; ni < 4; ++ni)
        bv[ni] = bias[col0 + wc * 64 + ni * 16 + l15];

#pragma unroll
    for (int mi = 0; mi < 4; ++mi) {
        int orow1 = row0 + wr * 64 + mi * 16 + l4 * 4;
        int orow2 = orow1 + 128;
#pragma unroll
        for (int ni = 0; ni < 4; ++ni) {
            int ocol = col0 + wc * 64 + ni * 16 + l15;
#pragma unroll
            for (int q = 0; q < 4; ++q) {
                Out[(size_t)(orow1 + q) * N + ocol] = f2bf(acc1[mi][ni][q] + bv[ni]);
                Out[(size_t)(orow2 + q) * N + ocol] = f2bf(acc2[mi][ni][q] + bv[ni]);
            }
        }
    }
}

// ---------------- combine ----------------

__global__ __launch_bounds__(256) void combine_k(
    const unsigned short* __restrict__ Y, const int* __restrict__ rev,
    const float* __restrict__ gates, const int* __restrict__ gidx,
    float* __restrict__ out) {
    int t = blockIdx.x;
    int r0 = rev[2 * t], r1 = rev[2 * t + 1];
    float g0 = gates[gidx[2 * t]], g1 = gates[gidx[2 * t + 1]];
    const unsigned short* y0 = Y + (size_t)r0 * DDIM;
    const unsigned short* y1 = Y + (size_t)r1 * DDIM;
    int d = threadIdx.x * 4;
    ushort4 a = *(const ushort4*)(y0 + d);
    ushort4 b = *(const ushort4*)(y1 + d);
    float4 r;
    r.x = g0 * bf2f(a.x) + g1 * bf2f(b.x);
    r.y = g0 * bf2f(a.y) + g1 * bf2f(b.y);
    r.z = g0 * bf2f(a.z) + g1 * bf2f(b.z);
    r.w = g0 * bf2f(a.w) + g1 * bf2f(b.w);
    *(float4*)(out + (size_t)t * DDIM + d) = r;
}

// ---------------- launch ----------------

extern "C" void kernel_launch(void* const* d_in, const int* in_sizes, int n_in,
                              void* d_out, int out_size, void* d_ws, size_t ws_size,
                              hipStream_t stream) {
    const int* offsets = (const int*)d_in[0];
    const float* jagged = (const float*)d_in[1];
    const float* weight = (const float*)d_in[2];
    const float* bias = (const float*)d_in[3];
    const int* index = (const int*)d_in[4];
    const float* weight_p = (const float*)d_in[5];
    const float* weight_out = (const float*)d_in[6];
    const int* rev = (const int*)d_in[7];
    const float* gates = (const float*)d_in[8];
    const int* gidx = (const int*)d_in[9];
    const float* bias_p = (const float*)d_in[10];
    const float* bias_out = (const float*)d_in[11];
    float* out = (float*)d_out;

    char* w = (char*)d_ws;
    unsigned short* jag_bf = (unsigned short*)w; w += (size_t)T_TOK * DDIM * 2;       // 16MB
    unsigned short* W1t    = (unsigned short*)w; w += (size_t)NEXP * DDIM * HDIM * 2; // 16MB
    unsigned short* Wpt    = (unsigned short*)w; w += (size_t)NEXP * DDIM * HDIM * 2; // 16MB
    unsigned short* Wot    = (unsigned short*)w; w += (size_t)NEXP * HDIM * DDIM * 2; // 16MB
    unsigned short* h_ws   = (unsigned short*)w; w += (size_t)NROWS * HDIM * 2;       // 32MB
    unsigned short* y_ws   = (unsigned short*)w; w += (size_t)NROWS * DDIM * 2;       // 32MB

    // prep: bf16 cast + merged weight transposes (B^T layout, 1 dispatch)
    cvt_bf16_k<<<(T_TOK * DDIM / 4 + 255) / 256, 256, 0, stream>>>(jagged, jag_bf, T_TOK * DDIM / 4);
    transpose_cast3_k<<<dim3(HDIM / 64, DDIM / 64, 3 * NEXP), 256, 0, stream>>>(
        weight, weight_p, weight_out, W1t, Wpt, Wot);

    const int grid = (NROWS / BMk) * (HDIM / BNk);    // 128 * 8 = 1024 blocks

    // h = silu(gather(x)@W + b) * (gather(x)@Wp + bp)   [FUSED, B-to-reg]
    gemm128_fused_k<<<grid, 256, 0, stream>>>(jag_bf, index, W1t, Wpt, bias, bias_p,
                                              h_ws, offsets);
    // y = h @ Wout + bout   [DUAL-ROW, B-to-reg]
    const int grid_y = (NROWS / 256) * (DDIM / BNk);  // 64 * 8 = 512 blocks
    gemm128_dualrow_k<<<grid_y, 256, 0, stream>>>(h_ws, HDIM, Wot, bias_out, y_ws,
                                                  offsets, DDIM, HDIM);
    // out[t] = sum_k gates[gidx[t,k]] * y[rev[t,k]]
    combine_k<<<T_TOK, 256, 0, stream>>>(y_ws, rev, gates, gidx, out);
}

// Round 21
// 158.295 us; speedup vs baseline: 1.5248x; 1.5248x over previous
//
#include <hip/hip_runtime.h>
#include <hip/hip_bf16.h>

#define T_TOK 8192
#define DDIM 1024
#define HDIM 1024
#define NEXP 8
#define KTOP 2
#define NROWS (T_TOK * KTOP)

typedef __attribute__((ext_vector_type(8))) short bf16x8;
typedef __attribute__((ext_vector_type(8))) unsigned short u16x8;
typedef __attribute__((ext_vector_type(4))) float f32x4;

__device__ __forceinline__ unsigned short f2bf(float f) {
    unsigned u = __builtin_bit_cast(unsigned, f);
    u += 0x7fffu + ((u >> 16) & 1u);   // RNE
    return (unsigned short)(u >> 16);
}
__device__ __forceinline__ float bf2f(unsigned short h) {
    return __builtin_bit_cast(float, (unsigned)h << 16);
}

// async global->LDS, 16B per lane; LDS dest wave-uniform base + lane*16.
__device__ __forceinline__ void gll16(const unsigned short* g, const unsigned short* l) {
    __builtin_amdgcn_global_load_lds(
        (const __attribute__((address_space(1))) unsigned int*)g,
        (__attribute__((address_space(3))) unsigned int*)l, 16, 0, 0);
}

// ---------------- prep kernels ----------------

__global__ __launch_bounds__(256) void cvt_bf16_k(const float* __restrict__ in,
                                                  unsigned short* __restrict__ out, int n4) {
    int i = blockIdx.x * 256 + threadIdx.x;
    if (i >= n4) return;
    float4 v = ((const float4*)in)[i];
    ushort4 o;
    o.x = f2bf(v.x); o.y = f2bf(v.y); o.z = f2bf(v.z); o.w = f2bf(v.w);
    ((ushort4*)out)[i] = o;
}

// merged transpose+cast, 64x64 tiles, 16B/lane coalesced writes (r15, verified).
__global__ __launch_bounds__(256) void transpose_cast3_k(
    const float* __restrict__ w1, const float* __restrict__ w2,
    const float* __restrict__ w3, unsigned short* __restrict__ o1,
    unsigned short* __restrict__ o2, unsigned short* __restrict__ o3) {
    __shared__ float tile[64][65];
    int z = blockIdx.z;
    int which = z >> 3, m = z & 7;
    const float* src = (which == 0 ? w1 : which == 1 ? w2 : w3) + (size_t)m * DDIM * HDIM;
    unsigned short* dst = (which == 0 ? o1 : which == 1 ? o2 : o3) + (size_t)m * DDIM * HDIM;
    int c0 = blockIdx.x * 64, r0 = blockIdx.y * 64;
    int t = threadIdx.x;
    int rr = t >> 4;
    int cc = (t & 15) * 4;
#pragma unroll
    for (int p = 0; p < 4; ++p) {
        float4 v = *(const float4*)&src[(size_t)(r0 + rr + p * 16) * HDIM + c0 + cc];
        tile[rr + p * 16][cc]     = v.x;
        tile[rr + p * 16][cc + 1] = v.y;
        tile[rr + p * 16][cc + 2] = v.z;
        tile[rr + p * 16][cc + 3] = v.w;
    }
    __syncthreads();
    int rb = (t & 7) * 8;
    int oc = t >> 3;
#pragma unroll
    for (int q = 0; q < 2; ++q) {
        int c = oc + q * 32;
        u16x8 o;
#pragma unroll
        for (int j = 0; j < 8; ++j)
            o[j] = f2bf(tile[rb + j][c]);
        *(u16x8*)&dst[(size_t)(c0 + c) * DDIM + r0 + rb] = o;
    }
}

// ---- FUSED gate+up: 128x128, A+B1 double-buffered, B2 single (r21) ------------
// h = silu(gather(x)@W1+b1) * (gather(x)@W2+b2). r20 ERRATUM: B-direct-to-reg
// put global latency in the MFMA chain (70->150us); B must flow through LDS
// (gll16 = the prefetch mechanism). r21: hide stage latency under compute via
// partial dbuf, using the full 160KB/CU: A dbuf 32K + B1 dbuf 32K + B2 16K =
// 80KB/block x 2 blocks = 160KB exactly. Per iter: issue A/B1(t+1) (8 gll16,
// into dead dbuf halves) -> compute(t) -> barrier1 (drains prefetch, had
// ~1300cyc to land; confirms B2 reads done) -> issue B2(t+1) (4 gll16) ->
// barrier2. Exposed staging 12 -> 4 loads/iter. WAR: dbuf halves last read in
// compute(t-1); B2 reads complete at barrier1. Plain __syncthreads throughout.
// Swizzle pair (A+B) verified r5-r19. XCD-chunked grid. (256,2): acc 128 AGPR
// + ~110 VGPR fits 2-wave budget (r17 spill lesson).

constexpr int BMk = 128, BNk = 128, BKk = 64;

__global__ __launch_bounds__(256, 2) void gemm128_fused_k(
    const unsigned short* __restrict__ A, const int* __restrict__ rowidx,
    const unsigned short* __restrict__ B1t, const unsigned short* __restrict__ B2t,
    const float* __restrict__ b1E, const float* __restrict__ b2E,
    unsigned short* __restrict__ Out, const int* __restrict__ offsets) {
    const int N = HDIM, K = DDIM, lda = DDIM;
    // ushort map: A buf b at b*8192; B1 buf b at 16384+b*8192; B2 at 32768. 80KB.
    __shared__ __attribute__((aligned(16))) unsigned short lds[40960];

    const int nbn = N / BNk;                          // 8
    int l = (blockIdx.x & 7) * 128 + (blockIdx.x >> 3);
    int brow = l / nbn, bcol = l % nbn;
    int row0 = brow * BMk, col0 = bcol * BNk;
    int e = 0;
    while (offsets[e + 1] <= row0) ++e;

    const unsigned short* B1e = B1t + (size_t)e * N * K;
    const unsigned short* B2e = B2t + (size_t)e * N * K;
    const float* b1 = b1E + (size_t)e * N;
    const float* b2 = b2E + (size_t)e * N;

    int tid = threadIdx.x;
    int lane = tid & 63, wid = tid >> 6;
    int wr = wid >> 1, wc = wid & 1;                  // 2x2 wave grid
    int l15 = lane & 15, l4 = lane >> 4;

    int srow = lane >> 3;
    int c8 = ((lane & 7) ^ srow) * 8;
    const unsigned short* aS[4];
    const unsigned short* b1S[4];
    const unsigned short* b2S[4];
#pragma unroll
    for (int q = 0; q < 4; ++q) {
        int g = wid * 4 + q;
        int gr = row0 + g * 8 + srow;
        aS[q]  = A + (size_t)rowidx[gr] * lda + c8;
        b1S[q] = B1e + (size_t)(col0 + g * 8 + srow) * K + c8;
        b2S[q] = B2e + (size_t)(col0 + g * 8 + srow) * K + c8;
    }

#define STG_A(T)  { int _b = (T) & 1; _Pragma("unroll") for (int q = 0; q < 4; ++q) \
        gll16(aS[q] + (T) * BKk, lds + _b * 8192 + (wid * 4 + q) * 512); }
#define STG_B1(T) { int _b = (T) & 1; _Pragma("unroll") for (int q = 0; q < 4; ++q) \
        gll16(b1S[q] + (T) * BKk, lds + 16384 + _b * 8192 + (wid * 4 + q) * 512); }
#define STG_B2(T) { _Pragma("unroll") for (int q = 0; q < 4; ++q) \
        gll16(b2S[q] + (T) * BKk, lds + 32768 + (wid * 4 + q) * 512); }

    const char* LB = (const char*)lds;
    int arow = (wr * 64 + l15) * 128;
    int brw = (wc * 64 + l15) * 128;
    int cx = l15 & 7;
    int ch0 = (l4 ^ cx) * 16;
    int ch1 = ((4 + l4) ^ cx) * 16;

    f32x4 acc1[4][4] = {};
    f32x4 acc2[4][4] = {};

    STG_A(0) STG_B1(0) STG_B2(0)
    __syncthreads();   // drains vmcnt(0): tile 0 ready

#pragma unroll 1
    for (int t = 0; t < K / BKk; ++t) {
        if (t + 1 < K / BKk) { STG_A(t + 1) STG_B1(t + 1) }   // into dead dbuf halves
        const char* Ab  = LB + (t & 1) * 16384;
        const char* B1b = LB + 32768 + (t & 1) * 16384;
        const char* B2b = LB + 65536;
#pragma unroll
        for (int s = 0; s < 2; ++s) {
            int ch = s ? ch1 : ch0;
            bf16x8 fa[4], fb1[4], fb2[4];
#pragma unroll
            for (int mi = 0; mi < 4; ++mi)
                fa[mi] = *(const bf16x8*)(Ab + arow + mi * 2048 + ch);
#pragma unroll
            for (int ni = 0; ni < 4; ++ni) {
                fb1[ni] = *(const bf16x8*)(B1b + brw + ni * 2048 + ch);
                fb2[ni] = *(const bf16x8*)(B2b + brw + ni * 2048 + ch);
            }
#pragma unroll
            for (int mi = 0; mi < 4; ++mi)
#pragma unroll
                for (int ni = 0; ni < 4; ++ni) {
                    acc1[mi][ni] = __builtin_amdgcn_mfma_f32_16x16x32_bf16(
                        fa[mi], fb1[ni], acc1[mi][ni], 0, 0, 0);
                    acc2[mi][ni] = __builtin_amdgcn_mfma_f32_16x16x32_bf16(
                        fa[mi], fb2[ni], acc2[mi][ni], 0, 0, 0);
                }
        }
        __syncthreads();   // B2 reads done by all; prefetch (A/B1 t+1) drained
        if (t + 1 < K / BKk) STG_B2(t + 1)
        __syncthreads();   // B2(t+1) landed + published
    }
#undef STG_A
#undef STG_B1
#undef STG_B2

    float bv1[4], bv2[4];
#pragma unroll
    for (int ni = 0; ni < 4; ++ni) {
        int c = col0 + wc * 64 + ni * 16 + l15;
        bv1[ni] = b1[c];
        bv2[ni] = b2[c];
    }

#pragma unroll
    for (int mi = 0; mi < 4; ++mi) {
        int orow_b = row0 + wr * 64 + mi * 16 + l4 * 4;
#pragma unroll
        for (int ni = 0; ni < 4; ++ni) {
            int ocol = col0 + wc * 64 + ni * 16 + l15;
#pragma unroll
            for (int q = 0; q < 4; ++q) {
                float g = acc1[mi][ni][q] + bv1[ni];
                float u = acc2[mi][ni][q] + bv2[ni];
                float s = g / (1.0f + __expf(-g));
                Out[(size_t)(orow_b + q) * N + ocol] = f2bf(s * u);
            }
        }
    }
}

// ---- DUAL-ROW y-GEMM: 256x128, A1+A2 double-buffered, B single (r21) ----------
// y = h @ Wout^T + bout. Two 128-row tiles share one B-tile (r19, 42us).
// Same partial-dbuf schedule: A1/A2(t+1) prefetched under compute (8 gll16),
// B(t+1) exposed (4 gll16). 80KB/block, 2 blocks/CU.

__global__ __launch_bounds__(256, 2) void gemm128_dualrow_k(
    const unsigned short* __restrict__ A, int lda,
    const unsigned short* __restrict__ Bt, const float* __restrict__ biasE,
    unsigned short* __restrict__ Out, const int* __restrict__ offsets,
    int N, int K) {
    // ushort map: A1 buf b at b*8192; A2 buf b at 16384+b*8192; B at 32768. 80KB.
    __shared__ __attribute__((aligned(16))) unsigned short lds[40960];

    const int nbn = N / BNk;                          // 8
    int l = (blockIdx.x & 7) * 64 + (blockIdx.x >> 3);
    int brow = l / nbn, bcol = l % nbn;               // brow: 0..63 (256-row units)
    int row0 = brow * 256, col0 = bcol * BNk;
    int e = 0;
    while (offsets[e + 1] <= row0) ++e;

    const unsigned short* Bte = Bt + (size_t)e * N * K;
    const float* bias = biasE + (size_t)e * N;

    int tid = threadIdx.x;
    int lane = tid & 63, wid = tid >> 6;
    int wr = wid >> 1, wc = wid & 1;                  // 2x2 wave grid
    int l15 = lane & 15, l4 = lane >> 4;

    int srow = lane >> 3;
    int c8 = ((lane & 7) ^ srow) * 8;
    const unsigned short* a1S[4];
    const unsigned short* a2S[4];
    const unsigned short* bS[4];
#pragma unroll
    for (int q = 0; q < 4; ++q) {
        int g = wid * 4 + q;
        a1S[q] = A + (size_t)(row0 + g * 8 + srow) * lda + c8;
        a2S[q] = A + (size_t)(row0 + 128 + g * 8 + srow) * lda + c8;
        bS[q]  = Bte + (size_t)(col0 + g * 8 + srow) * K + c8;
    }

#define STG_A1(T) { int _b = (T) & 1; _Pragma("unroll") for (int q = 0; q < 4; ++q) \
        gll16(a1S[q] + (T) * BKk, lds + _b * 8192 + (wid * 4 + q) * 512); }
#define STG_A2(T) { int _b = (T) & 1; _Pragma("unroll") for (int q = 0; q < 4; ++q) \
        gll16(a2S[q] + (T) * BKk, lds + 16384 + _b * 8192 + (wid * 4 + q) * 512); }
#define STG_B(T)  { _Pragma("unroll") for (int q = 0; q < 4; ++q) \
        gll16(bS[q] + (T) * BKk, lds + 32768 + (wid * 4 + q) * 512); }

    const char* LB = (const char*)lds;
    int arow = (wr * 64 + l15) * 128;                 // byte, within each A tile
    int brw = (wc * 64 + l15) * 128;                  // byte, within B tile
    int cx = l15 & 7;
    int ch0 = (l4 ^ cx) * 16;
    int ch1 = ((4 + l4) ^ cx) * 16;

    f32x4 acc1[4][4] = {};
    f32x4 acc2[4][4] = {};

    STG_A1(0) STG_A2(0) STG_B(0)
    __syncthreads();

#pragma unroll 1
    for (int t = 0; t < K / BKk; ++t) {
        if (t + 1 < K / BKk) { STG_A1(t + 1) STG_A2(t + 1) }   // dead dbuf halves
        const char* A1b = LB + (t & 1) * 16384;
        const char* A2b = LB + 32768 + (t & 1) * 16384;
        const char* Bb  = LB + 65536;
#pragma unroll
        for (int s = 0; s < 2; ++s) {
            int ch = s ? ch1 : ch0;
            bf16x8 fa1[4], fa2[4], fb[4];
#pragma unroll
            for (int mi = 0; mi < 4; ++mi) {
                fa1[mi] = *(const bf16x8*)(A1b + arow + mi * 2048 + ch);
                fa2[mi] = *(const bf16x8*)(A2b + arow + mi * 2048 + ch);
            }
#pragma unroll
            for (int ni = 0; ni < 4; ++ni)
                fb[ni] = *(const bf16x8*)(Bb + brw + ni * 2048 + ch);
#pragma unroll
            for (int mi = 0; mi < 4; ++mi)
#pragma unroll
                for (int ni = 0; ni < 4; ++ni) {
                    acc1[mi][ni] = __builtin_amdgcn_mfma_f32_16x16x32_bf16(
                        fa1[mi], fb[ni], acc1[mi][ni], 0, 0, 0);
                    acc2[mi][ni] = __builtin_amdgcn_mfma_f32_16x16x32_bf16(
                        fa2[mi], fb[ni], acc2[mi][ni], 0, 0, 0);
                }
        }
        __syncthreads();   // B reads done; A prefetch drained
        if (t + 1 < K / BKk) STG_B(t + 1)
        __syncthreads();   // B(t+1) landed + published
    }
#undef STG_A1
#undef STG_A2
#undef STG_B

    float bv[4];
#pragma unroll
    for (int ni = 0; ni < 4; ++ni)
        bv[ni] = bias[col0 + wc * 64 + ni * 16 + l15];

#pragma unroll
    for (int mi = 0; mi < 4; ++mi) {
        int orow1 = row0 + wr * 64 + mi * 16 + l4 * 4;
        int orow2 = orow1 + 128;
#pragma unroll
        for (int ni = 0; ni < 4; ++ni) {
            int ocol = col0 + wc * 64 + ni * 16 + l15;
#pragma unroll
            for (int q = 0; q < 4; ++q) {
                Out[(size_t)(orow1 + q) * N + ocol] = f2bf(acc1[mi][ni][q] + bv[ni]);
                Out[(size_t)(orow2 + q) * N + ocol] = f2bf(acc2[mi][ni][q] + bv[ni]);
            }
        }
    }
}

// ---------------- combine ----------------

__global__ __launch_bounds__(256) void combine_k(
    const unsigned short* __restrict__ Y, const int* __restrict__ rev,
    const float* __restrict__ gates, const int* __restrict__ gidx,
    float* __restrict__ out) {
    int t = blockIdx.x;
    int r0 = rev[2 * t], r1 = rev[2 * t + 1];
    float g0 = gates[gidx[2 * t]], g1 = gates[gidx[2 * t + 1]];
    const unsigned short* y0 = Y + (size_t)r0 * DDIM;
    const unsigned short* y1 = Y + (size_t)r1 * DDIM;
    int d = threadIdx.x * 4;
    ushort4 a = *(const ushort4*)(y0 + d);
    ushort4 b = *(const ushort4*)(y1 + d);
    float4 r;
    r.x = g0 * bf2f(a.x) + g1 * bf2f(b.x);
    r.y = g0 * bf2f(a.y) + g1 * bf2f(b.y);
    r.z = g0 * bf2f(a.z) + g1 * bf2f(b.z);
    r.w = g0 * bf2f(a.w) + g1 * bf2f(b.w);
    *(float4*)(out + (size_t)t * DDIM + d) = r;
}

// ---------------- launch ----------------

extern "C" void kernel_launch(void* const* d_in, const int* in_sizes, int n_in,
                              void* d_out, int out_size, void* d_ws, size_t ws_size,
                              hipStream_t stream) {
    const int* offsets = (const int*)d_in[0];
    const float* jagged = (const float*)d_in[1];
    const float* weight = (const float*)d_in[2];
    const float* bias = (const float*)d_in[3];
    const int* index = (const int*)d_in[4];
    const float* weight_p = (const float*)d_in[5];
    const float* weight_out = (const float*)d_in[6];
    const int* rev = (const int*)d_in[7];
    const float* gates = (const float*)d_in[8];
    const int* gidx = (const int*)d_in[9];
    const float* bias_p = (const float*)d_in[10];
    const float* bias_out = (const float*)d_in[11];
    float* out = (float*)d_out;

    char* w = (char*)d_ws;
    unsigned short* jag_bf = (unsigned short*)w; w += (size_t)T_TOK * DDIM * 2;       // 16MB
    unsigned short* W1t    = (unsigned short*)w; w += (size_t)NEXP * DDIM * HDIM * 2; // 16MB
    unsigned short* Wpt    = (unsigned short*)w; w += (size_t)NEXP * DDIM * HDIM * 2; // 16MB
    unsigned short* Wot    = (unsigned short*)w; w += (size_t)NEXP * HDIM * DDIM * 2; // 16MB
    unsigned short* h_ws   = (unsigned short*)w; w += (size_t)NROWS * HDIM * 2;       // 32MB
    unsigned short* y_ws   = (unsigned short*)w; w += (size_t)NROWS * DDIM * 2;       // 32MB

    // prep: bf16 cast + merged weight transposes (B^T layout, 1 dispatch)
    cvt_bf16_k<<<(T_TOK * DDIM / 4 + 255) / 256, 256, 0, stream>>>(jagged, jag_bf, T_TOK * DDIM / 4);
    transpose_cast3_k<<<dim3(HDIM / 64, DDIM / 64, 3 * NEXP), 256, 0, stream>>>(
        weight, weight_p, weight_out, W1t, Wpt, Wot);

    const int grid = (NROWS / BMk) * (HDIM / BNk);    // 128 * 8 = 1024 blocks

    // h = silu(gather(x)@W + b) * (gather(x)@Wp + bp)   [FUSED, partial dbuf]
    gemm128_fused_k<<<grid, 256, 0, stream>>>(jag_bf, index, W1t, Wpt, bias, bias_p,
                                              h_ws, offsets);
    // y = h @ Wout + bout   [DUAL-ROW, partial dbuf]
    const int grid_y = (NROWS / 256) * (DDIM / BNk);  // 64 * 8 = 512 blocks
    gemm128_dualrow_k<<<grid_y, 256, 0, stream>>>(h_ws, HDIM, Wot, bias_out, y_ws,
                                                  offsets, DDIM, HDIM);
    // out[t] = sum_k gates[gidx[t,k]] * y[rev[t,k]]
    combine_k<<<T_TOK, 256, 0, stream>>>(y_ws, rev, gates, gidx, out);
}

// Round 22
// 154.926 us; speedup vs baseline: 1.5580x; 1.0217x over previous
//
#include <hip/hip_runtime.h>
#include <hip/hip_bf16.h>

#define T_TOK 8192
#define DDIM 1024
#define HDIM 1024
#define NEXP 8
#define KTOP 2
#define NROWS (T_TOK * KTOP)

typedef __attribute__((ext_vector_type(8))) short bf16x8;
typedef __attribute__((ext_vector_type(8))) unsigned short u16x8;
typedef __attribute__((ext_vector_type(4))) float f32x4;

__device__ __forceinline__ unsigned short f2bf(float f) {
    unsigned u = __builtin_bit_cast(unsigned, f);
    u += 0x7fffu + ((u >> 16) & 1u);   // RNE
    return (unsigned short)(u >> 16);
}
__device__ __forceinline__ float bf2f(unsigned short h) {
    return __builtin_bit_cast(float, (unsigned)h << 16);
}

// async global->LDS, 16B per lane; LDS dest wave-uniform base + lane*16.
__device__ __forceinline__ void gll16(const unsigned short* g, const unsigned short* l) {
    __builtin_amdgcn_global_load_lds(
        (const __attribute__((address_space(1))) unsigned int*)g,
        (__attribute__((address_space(3))) unsigned int*)l, 16, 0, 0);
}

// ---------------- prep kernels ----------------

__global__ __launch_bounds__(256) void cvt_bf16_k(const float* __restrict__ in,
                                                  unsigned short* __restrict__ out, int n4) {
    int i = blockIdx.x * 256 + threadIdx.x;
    if (i >= n4) return;
    float4 v = ((const float4*)in)[i];
    ushort4 o;
    o.x = f2bf(v.x); o.y = f2bf(v.y); o.z = f2bf(v.z); o.w = f2bf(v.w);
    ((ushort4*)out)[i] = o;
}

// merged transpose+cast, 64x64 tiles, 16B/lane coalesced writes (r15, verified).
__global__ __launch_bounds__(256) void transpose_cast3_k(
    const float* __restrict__ w1, const float* __restrict__ w2,
    const float* __restrict__ w3, unsigned short* __restrict__ o1,
    unsigned short* __restrict__ o2, unsigned short* __restrict__ o3) {
    __shared__ float tile[64][65];
    int z = blockIdx.z;
    int which = z >> 3, m = z & 7;
    const float* src = (which == 0 ? w1 : which == 1 ? w2 : w3) + (size_t)m * DDIM * HDIM;
    unsigned short* dst = (which == 0 ? o1 : which == 1 ? o2 : o3) + (size_t)m * DDIM * HDIM;
    int c0 = blockIdx.x * 64, r0 = blockIdx.y * 64;
    int t = threadIdx.x;
    int rr = t >> 4;
    int cc = (t & 15) * 4;
#pragma unroll
    for (int p = 0; p < 4; ++p) {
        float4 v = *(const float4*)&src[(size_t)(r0 + rr + p * 16) * HDIM + c0 + cc];
        tile[rr + p * 16][cc]     = v.x;
        tile[rr + p * 16][cc + 1] = v.y;
        tile[rr + p * 16][cc + 2] = v.z;
        tile[rr + p * 16][cc + 3] = v.w;
    }
    __syncthreads();
    int rb = (t & 7) * 8;
    int oc = t >> 3;
#pragma unroll
    for (int q = 0; q < 2; ++q) {
        int c = oc + q * 32;
        u16x8 o;
#pragma unroll
        for (int j = 0; j < 8; ++j)
            o[j] = f2bf(tile[rb + j][c]);
        *(u16x8*)&dst[(size_t)(c0 + c) * DDIM + r0 + rb] = o;
    }
}

// ---- FUSED gate+up: 128x128 tile, dual-B, 2 blocks/CU (r18/r19, verified) -----
// h = silu(gather(x)@W1+b1) * (gather(x)@W2+b2). A staged ONCE feeds both
// matmuls -> 64 MFMA/wave per stage/drain latency chain = 981 TF effective.
// LOCAL OPTIMUM (r20/r21 A/B): B-direct-to-reg exposes L2 latency in the MFMA
// chain (70->150us); partial dbuf+extra barrier is neutral-to-worse (73us).
// (256,2): acc 128 AGPR + 104 VGPR needs the 2-wave budget (r17's (256,3)
// spilled acc -> 253us). Swizzle pair verified r5-r19. XCD-chunked grid.

constexpr int BMk = 128, BNk = 128, BKk = 64;

__global__ __launch_bounds__(256, 2) void gemm128_fused_k(
    const unsigned short* __restrict__ A, const int* __restrict__ rowidx,
    const unsigned short* __restrict__ B1t, const unsigned short* __restrict__ B2t,
    const float* __restrict__ b1E, const float* __restrict__ b2E,
    unsigned short* __restrict__ Out, const int* __restrict__ offsets) {
    const int N = HDIM, K = DDIM, lda = DDIM;
    __shared__ __attribute__((aligned(16))) unsigned short lds[24576];  // 48 KiB

    const int nbn = N / BNk;                          // 8
    int l = (blockIdx.x & 7) * 128 + (blockIdx.x >> 3);
    int brow = l / nbn, bcol = l % nbn;
    int row0 = brow * BMk, col0 = bcol * BNk;
    int e = 0;
    while (offsets[e + 1] <= row0) ++e;

    const unsigned short* B1e = B1t + (size_t)e * N * K;
    const unsigned short* B2e = B2t + (size_t)e * N * K;
    const float* b1 = b1E + (size_t)e * N;
    const float* b2 = b2E + (size_t)e * N;

    int tid = threadIdx.x;
    int lane = tid & 63, wid = tid >> 6;
    int wr = wid >> 1, wc = wid & 1;                  // 2x2 wave grid
    int l15 = lane & 15, l4 = lane >> 4;

    int srow = lane >> 3;
    int c8 = ((lane & 7) ^ srow) * 8;
    const unsigned short* aS[4];
    const unsigned short* b1S[4];
    const unsigned short* b2S[4];
#pragma unroll
    for (int q = 0; q < 4; ++q) {
        int g = wid * 4 + q;
        int gr = row0 + g * 8 + srow;
        aS[q]  = A + (size_t)rowidx[gr] * lda + c8;
        b1S[q] = B1e + (size_t)(col0 + g * 8 + srow) * K + c8;
        b2S[q] = B2e + (size_t)(col0 + g * 8 + srow) * K + c8;
    }

    const char* LB = (const char*)lds;
    int arow = (wr * 64 + l15) * 128;
    int brw = (wc * 64 + l15) * 128;
    int cx = l15 & 7;
    int ch0 = (l4 ^ cx) * 16;
    int ch1 = ((4 + l4) ^ cx) * 16;

    f32x4 acc1[4][4] = {};
    f32x4 acc2[4][4] = {};

#pragma unroll 1
    for (int t = 0; t < K / BKk; ++t) {
        int k0 = t * BKk;
#pragma unroll
        for (int q = 0; q < 4; ++q) {
            gll16(aS[q] + k0,  lds + (wid * 4 + q) * 512);
            gll16(b1S[q] + k0, lds + 8192 + (wid * 4 + q) * 512);
            gll16(b2S[q] + k0, lds + 16384 + (wid * 4 + q) * 512);
        }
        __syncthreads();   // drains vmcnt(0); co-resident block hides the wait
#pragma unroll
        for (int s = 0; s < 2; ++s) {
            int ch = s ? ch1 : ch0;
            bf16x8 fa[4], fb1[4], fb2[4];
#pragma unroll
            for (int mi = 0; mi < 4; ++mi)
                fa[mi] = *(const bf16x8*)(LB + arow + mi * 2048 + ch);
#pragma unroll
            for (int ni = 0; ni < 4; ++ni) {
                fb1[ni] = *(const bf16x8*)(LB + 8192 * 2 + brw + ni * 2048 + ch);
                fb2[ni] = *(const bf16x8*)(LB + 8192 * 4 + brw + ni * 2048 + ch);
            }
#pragma unroll
            for (int mi = 0; mi < 4; ++mi)
#pragma unroll
                for (int ni = 0; ni < 4; ++ni) {
                    acc1[mi][ni] = __builtin_amdgcn_mfma_f32_16x16x32_bf16(
                        fa[mi], fb1[ni], acc1[mi][ni], 0, 0, 0);
                    acc2[mi][ni] = __builtin_amdgcn_mfma_f32_16x16x32_bf16(
                        fa[mi], fb2[ni], acc2[mi][ni], 0, 0, 0);
                }
        }
        __syncthreads();   // reads done before next stage overwrites
    }

    float bv1[4], bv2[4];
#pragma unroll
    for (int ni = 0; ni < 4; ++ni) {
        int c = col0 + wc * 64 + ni * 16 + l15;
        bv1[ni] = b1[c];
        bv2[ni] = b2[c];
    }

#pragma unroll
    for (int mi = 0; mi < 4; ++mi) {
        int orow_b = row0 + wr * 64 + mi * 16 + l4 * 4;
#pragma unroll
        for (int ni = 0; ni < 4; ++ni) {
            int ocol = col0 + wc * 64 + ni * 16 + l15;
#pragma unroll
            for (int q = 0; q < 4; ++q) {
                float g = acc1[mi][ni][q] + bv1[ni];
                float u = acc2[mi][ni][q] + bv2[ni];
                float s = g / (1.0f + __expf(-g));
                Out[(size_t)(orow_b + q) * N + ocol] = f2bf(s * u);
            }
        }
    }
}

// ---- DUAL-ROW y-GEMM: 256x128 block, two row-tiles share one B (r19) ----------
// y = h @ Wout^T + bout. Per iter: stage A1+A2+B (48KB LDS) -> 64 MFMA/wave;
// one stage/drain chain for 2 tiles of work (~42us, vs 45.2 single + half the
// dispatches). (256,2); 2 blocks/CU. XCD chunk: 64 blocks/XCD = expert x.

__global__ __launch_bounds__(256, 2) void gemm128_dualrow_k(
    const unsigned short* __restrict__ A, int lda,
    const unsigned short* __restrict__ Bt, const float* __restrict__ biasE,
    unsigned short* __restrict__ Out, const int* __restrict__ offsets,
    int N, int K) {
    __shared__ __attribute__((aligned(16))) unsigned short lds[24576];  // 48 KiB

    const int nbn = N / BNk;                          // 8
    int l = (blockIdx.x & 7) * 64 + (blockIdx.x >> 3);
    int brow = l / nbn, bcol = l % nbn;               // brow: 0..63 (256-row units)
    int row0 = brow * 256, col0 = bcol * BNk;
    int e = 0;
    while (offsets[e + 1] <= row0) ++e;

    const unsigned short* Bte = Bt + (size_t)e * N * K;
    const float* bias = biasE + (size_t)e * N;

    int tid = threadIdx.x;
    int lane = tid & 63, wid = tid >> 6;
    int wr = wid >> 1, wc = wid & 1;                  // 2x2 wave grid
    int l15 = lane & 15, l4 = lane >> 4;

    int srow = lane >> 3;
    int c8 = ((lane & 7) ^ srow) * 8;
    const unsigned short* a1S[4];
    const unsigned short* a2S[4];
    const unsigned short* bS[4];
#pragma unroll
    for (int q = 0; q < 4; ++q) {
        int g = wid * 4 + q;
        a1S[q] = A + (size_t)(row0 + g * 8 + srow) * lda + c8;
        a2S[q] = A + (size_t)(row0 + 128 + g * 8 + srow) * lda + c8;
        bS[q]  = Bte + (size_t)(col0 + g * 8 + srow) * K + c8;
    }

    const char* LB = (const char*)lds;
    int arow = (wr * 64 + l15) * 128;                 // byte, within each A tile
    int brw = (wc * 64 + l15) * 128;                  // byte, within B tile
    int cx = l15 & 7;
    int ch0 = (l4 ^ cx) * 16;
    int ch1 = ((4 + l4) ^ cx) * 16;

    f32x4 acc1[4][4] = {};
    f32x4 acc2[4][4] = {};

#pragma unroll 1
    for (int t = 0; t < K / BKk; ++t) {
        int k0 = t * BKk;
#pragma unroll
        for (int q = 0; q < 4; ++q) {
            gll16(a1S[q] + k0, lds + (wid * 4 + q) * 512);
            gll16(a2S[q] + k0, lds + 8192 + (wid * 4 + q) * 512);
            gll16(bS[q] + k0,  lds + 16384 + (wid * 4 + q) * 512);
        }
        __syncthreads();   // drains vmcnt(0); co-resident block hides the wait
#pragma unroll
        for (int s = 0; s < 2; ++s) {
            int ch = s ? ch1 : ch0;
            bf16x8 fa1[4], fa2[4], fb[4];
#pragma unroll
            for (int mi = 0; mi < 4; ++mi) {
                fa1[mi] = *(const bf16x8*)(LB + arow + mi * 2048 + ch);
                fa2[mi] = *(const bf16x8*)(LB + 16384 + arow + mi * 2048 + ch);
            }
#pragma unroll
            for (int ni = 0; ni < 4; ++ni)
                fb[ni] = *(const bf16x8*)(LB + 32768 + brw + ni * 2048 + ch);
#pragma unroll
            for (int mi = 0; mi < 4; ++mi)
#pragma unroll
                for (int ni = 0; ni < 4; ++ni) {
                    acc1[mi][ni] = __builtin_amdgcn_mfma_f32_16x16x32_bf16(
                        fa1[mi], fb[ni], acc1[mi][ni], 0, 0, 0);
                    acc2[mi][ni] = __builtin_amdgcn_mfma_f32_16x16x32_bf16(
                        fa2[mi], fb[ni], acc2[mi][ni], 0, 0, 0);
                }
        }
        __syncthreads();   // reads done before next stage overwrites
    }

    float bv[4];
#pragma unroll
    for (int ni = 0; ni < 4; ++ni)
        bv[ni] = bias[col0 + wc * 64 + ni * 16 + l15];

#pragma unroll
    for (int mi = 0; mi < 4; ++mi) {
        int orow1 = row0 + wr * 64 + mi * 16 + l4 * 4;
        int orow2 = orow1 + 128;
#pragma unroll
        for (int ni = 0; ni < 4; ++ni) {
            int ocol = col0 + wc * 64 + ni * 16 + l15;
#pragma unroll
            for (int q = 0; q < 4; ++q) {
                Out[(size_t)(orow1 + q) * N + ocol] = f2bf(acc1[mi][ni][q] + bv[ni]);
                Out[(size_t)(orow2 + q) * N + ocol] = f2bf(acc2[mi][ni][q] + bv[ni]);
            }
        }
    }
}

// ---------------- combine ----------------

__global__ __launch_bounds__(256) void combine_k(
    const unsigned short* __restrict__ Y, const int* __restrict__ rev,
    const float* __restrict__ gates, const int* __restrict__ gidx,
    float* __restrict__ out) {
    int t = blockIdx.x;
    int r0 = rev[2 * t], r1 = rev[2 * t + 1];
    float g0 = gates[gidx[2 * t]], g1 = gates[gidx[2 * t + 1]];
    const unsigned short* y0 = Y + (size_t)r0 * DDIM;
    const unsigned short* y1 = Y + (size_t)r1 * DDIM;
    int d = threadIdx.x * 4;
    ushort4 a = *(const ushort4*)(y0 + d);
    ushort4 b = *(const ushort4*)(y1 + d);
    float4 r;
    r.x = g0 * bf2f(a.x) + g1 * bf2f(b.x);
    r.y = g0 * bf2f(a.y) + g1 * bf2f(b.y);
    r.z = g0 * bf2f(a.z) + g1 * bf2f(b.z);
    r.w = g0 * bf2f(a.w) + g1 * bf2f(b.w);
    *(float4*)(out + (size_t)t * DDIM + d) = r;
}

// ---------------- launch ----------------

extern "C" void kernel_launch(void* const* d_in, const int* in_sizes, int n_in,
                              void* d_out, int out_size, void* d_ws, size_t ws_size,
                              hipStream_t stream) {
    const int* offsets = (const int*)d_in[0];
    const float* jagged = (const float*)d_in[1];
    const float* weight = (const float*)d_in[2];
    const float* bias = (const float*)d_in[3];
    const int* index = (const int*)d_in[4];
    const float* weight_p = (const float*)d_in[5];
    const float* weight_out = (const float*)d_in[6];
    const int* rev = (const int*)d_in[7];
    const float* gates = (const float*)d_in[8];
    const int* gidx = (const int*)d_in[9];
    const float* bias_p = (const float*)d_in[10];
    const float* bias_out = (const float*)d_in[11];
    float* out = (float*)d_out;

    char* w = (char*)d_ws;
    unsigned short* jag_bf = (unsigned short*)w; w += (size_t)T_TOK * DDIM * 2;       // 16MB
    unsigned short* W1t    = (unsigned short*)w; w += (size_t)NEXP * DDIM * HDIM * 2; // 16MB
    unsigned short* Wpt    = (unsigned short*)w; w += (size_t)NEXP * DDIM * HDIM * 2; // 16MB
    unsigned short* Wot    = (unsigned short*)w; w += (size_t)NEXP * HDIM * DDIM * 2; // 16MB
    unsigned short* h_ws   = (unsigned short*)w; w += (size_t)NROWS * HDIM * 2;       // 32MB
    unsigned short* y_ws   = (unsigned short*)w; w += (size_t)NROWS * DDIM * 2;       // 32MB

    // prep: bf16 cast + merged weight transposes (B^T layout, 1 dispatch)
    cvt_bf16_k<<<(T_TOK * DDIM / 4 + 255) / 256, 256, 0, stream>>>(jagged, jag_bf, T_TOK * DDIM / 4);
    transpose_cast3_k<<<dim3(HDIM / 64, DDIM / 64, 3 * NEXP), 256, 0, stream>>>(
        weight, weight_p, weight_out, W1t, Wpt, Wot);

    const int grid = (NROWS / BMk) * (HDIM / BNk);    // 128 * 8 = 1024 blocks

    // h = silu(gather(x)@W + b) * (gather(x)@Wp + bp)   [FUSED: A staged once]
    gemm128_fused_k<<<grid, 256, 0, stream>>>(jag_bf, index, W1t, Wpt, bias, bias_p,
                                              h_ws, offsets);
    // y = h @ Wout + bout   [DUAL-ROW: B staged once for two row-tiles]
    const int grid_y = (NROWS / 256) * (DDIM / BNk);  // 64 * 8 = 512 blocks
    gemm128_dualrow_k<<<grid_y, 256, 0, stream>>>(h_ws, HDIM, Wot, bias_out, y_ws,
                                                  offsets, DDIM, HDIM);
    // out[t] = sum_k gates[gidx[t,k]] * y[rev[t,k]]
    combine_k<<<T_TOK, 256, 0, stream>>>(y_ws, rev, gates, gidx, out);
}